// Round 1
// baseline (1807.968 us; speedup 1.0000x reference)
//
#include <hip/hip_runtime.h>

// EagerRNN: B=64, T=512, F=512, H=1024.
// xproj = x @ W[:512] + b  (32768x1024x512 GEMM)
// scan:  state = tanh(xproj[:,t,:] + state @ W[512:])   512 sequential steps
// out: final state (64,1024) f32.
//
// All matmuls in FP16 (mfma_f32_16x16x32_f16), accumulation f32.
// Phase 2 is a persistent 64-block kernel: 4 batch-groups x 16 N-slices.
// Cross-WG state exchange via agent-scope (coherent) atomics. This revision:
//  - per-producer monotonic FLAGS (no contended fetch_add barrier; wave w
//    polls only its 4 producers' flags = one 128B line, then loads those
//    slices immediately)
//  - state stores packed to one 8B coherent store per thread (wave-local
//    LDS transpose; 4-aligned col groups stay contiguous under the swizzle)
//  - Wh slice fully register-resident (32 x f16x8 per lane), no Wh LDS
//    image, no per-step B-fragment LDS reads.

typedef _Float16 f16;
typedef _Float16 f16x8 __attribute__((ext_vector_type(8)));
typedef _Float16 f16x4 __attribute__((ext_vector_type(4)));
typedef float f32x4 __attribute__((ext_vector_type(4)));

#define B_  64
#define T_  512
#define F_  512
#define H_  1024

// workspace layout (bytes)
#define XPH_OFF  0ull                         // f16 [T][B][H]  = 64 MB
#define WXT_OFF  67108864ull                  // f16 [H][F]     = 1 MB
#define WHT_OFF  68157440ull                  // f16 [H][H]     = 2 MB
#define SBUF_OFF 70254592ull                  // f16 image, 2 parities x 4 groups x 32768 B
#define BAR_OFF  70516736ull                  // 64 flags x 32B = 2048 B
#define WS_NEED  70518784ull

// ---------------------------------------------------------------------------
// prep: W f32 [1536][1024] -> WxT f16 [h][k<512], WhT f16 [h][k<1024] (k-major
// per output column so MFMA B-fragments are contiguous 16B reads)
__global__ __launch_bounds__(256) void k_prep(const float* __restrict__ W,
                                              f16* __restrict__ WxT,
                                              f16* __restrict__ WhT) {
  __shared__ float tile[32][33];
  const int tid = threadIdx.x;
  const int kt = blockIdx.x >> 5;   // 0..47 (32 k-rows each)
  const int ht = blockIdx.x & 31;   // 0..31 (32 h-cols each)
#pragma unroll
  for (int p = 0; p < 4; ++p) {
    int kr = p * 8 + (tid >> 5);
    tile[kr][tid & 31] = W[(size_t)(kt * 32 + kr) * 1024 + ht * 32 + (tid & 31)];
  }
  __syncthreads();
  const int hl = tid >> 3;   // 0..31
  const int kq = tid & 7;    // 0..7  -> 4 k each
  f16x4 v;
#pragma unroll
  for (int j = 0; j < 4; ++j) v[j] = (f16)tile[kq * 4 + j][hl];
  const int h = ht * 32 + hl;
  const int kg = kt * 32 + kq * 4;
  if (kg < 512) *(f16x4*)(WxT + (size_t)h * 512 + kg) = v;
  else          *(f16x4*)(WhT + (size_t)h * 1024 + (kg - 512)) = v;
}

// ---------------------------------------------------------------------------
// phase 1: xph[t*64+b][h] = f16( x[b][t][:] @ Wx[:][h] + bias[h] )
// One block per 64 M-rows; loops all 16 N-blocks with A resident in LDS
// (x rows read exactly once from HBM). LDS: A 64KB + B 64KB = 128 KB.
__global__ __launch_bounds__(256) void k_xproj(const float* __restrict__ x,
                                               const f16* __restrict__ WxT,
                                               const float* __restrict__ bias,
                                               f16* __restrict__ xph) {
  __shared__ __align__(16) unsigned char Al[65536];  // [64 m][512 k] f16, swizzled
  __shared__ __align__(16) unsigned char Bl[65536];  // [64 n][512 k] f16, swizzled
  const int tid = threadIdx.x;
  const int l = tid & 63, w = tid >> 6;
  const int lane15 = l & 15, sub = l >> 4;
  const int m0 = blockIdx.x * 64;
  const int bidx = m0 >> 9;     // batch
  const int t0 = m0 & 511;      // time base (tile never crosses batch bound)

  // stage A once: thread t handles row r=tid>>2, k-quarter qq=tid&3
  {
    const int r = tid >> 2, qq = tid & 3;
    const float* xs = x + (size_t)(m0 + r) * 512;
#pragma unroll
    for (int i = 0; i < 16; ++i) {
      int s = qq * 16 + i;          // 16B slot 0..63
      int c = s ^ (r & 7);          // source k-chunk (swizzle on source)
      const float4 f0 = *(const float4*)(xs + c * 8);
      const float4 f1 = *(const float4*)(xs + c * 8 + 4);
      f16x8 v;
      v[0] = (f16)f0.x; v[1] = (f16)f0.y; v[2] = (f16)f0.z; v[3] = (f16)f0.w;
      v[4] = (f16)f1.x; v[5] = (f16)f1.y; v[6] = (f16)f1.z; v[7] = (f16)f1.w;
      *(f16x8*)(Al + r * 1024 + s * 16) = v;
    }
  }

  const int mh = (w >> 1) * 32, nh = (w & 1) * 32;
  const int rA0 = mh + lane15, rA1 = mh + 16 + lane15;
  const int rB0 = nh + lane15, rB1 = nh + 16 + lane15;

  for (int nb = 0; nb < 16; ++nb) {
    const int n0 = nb * 64;
    __syncthreads();   // Bl safe to overwrite
    {
      const int r = tid >> 2, qq = tid & 3;
      const f16* bs = WxT + (size_t)(n0 + r) * 512;
#pragma unroll
      for (int i = 0; i < 16; ++i) {
        int s = qq * 16 + i;
        int c = s ^ (r & 7);
        f16x8 v = *(const f16x8*)(bs + c * 8);
        *(f16x8*)(Bl + r * 1024 + s * 16) = v;
      }
    }
    __syncthreads();
    f32x4 acc00 = {0.f,0.f,0.f,0.f}, acc01 = {0.f,0.f,0.f,0.f};
    f32x4 acc10 = {0.f,0.f,0.f,0.f}, acc11 = {0.f,0.f,0.f,0.f};
#pragma unroll
    for (int kk = 0; kk < 16; ++kk) {
      const int s = kk * 4 + sub;
      f16x8 a0 = *(const f16x8*)(Al + rA0 * 1024 + ((s ^ (rA0 & 7)) << 4));
      f16x8 a1 = *(const f16x8*)(Al + rA1 * 1024 + ((s ^ (rA1 & 7)) << 4));
      f16x8 b0 = *(const f16x8*)(Bl + rB0 * 1024 + ((s ^ (rB0 & 7)) << 4));
      f16x8 b1 = *(const f16x8*)(Bl + rB1 * 1024 + ((s ^ (rB1 & 7)) << 4));
      acc00 = __builtin_amdgcn_mfma_f32_16x16x32_f16(a0, b0, acc00, 0, 0, 0);
      acc01 = __builtin_amdgcn_mfma_f32_16x16x32_f16(a0, b1, acc01, 0, 0, 0);
      acc10 = __builtin_amdgcn_mfma_f32_16x16x32_f16(a1, b0, acc10, 0, 0, 0);
      acc11 = __builtin_amdgcn_mfma_f32_16x16x32_f16(a1, b1, acc11, 0, 0, 0);
    }
    const float bv0 = bias[n0 + nh + lane15];
    const float bv1 = bias[n0 + nh + 16 + lane15];
#pragma unroll
    for (int j = 0; j < 4; ++j) {
      const int r0 = mh + sub * 4 + j;
      const int r1 = mh + 16 + sub * 4 + j;
      const size_t row0 = (size_t)(t0 + r0) * 64 + bidx;
      const size_t row1 = (size_t)(t0 + r1) * 64 + bidx;
      xph[row0 * 1024 + n0 + nh + lane15]      = (f16)(acc00[j] + bv0);
      xph[row0 * 1024 + n0 + nh + 16 + lane15] = (f16)(acc01[j] + bv1);
      xph[row1 * 1024 + n0 + nh + lane15]      = (f16)(acc10[j] + bv0);
      xph[row1 * 1024 + n0 + nh + 16 + lane15] = (f16)(acc11[j] + bv1);
    }
  }
}

// ---------------------------------------------------------------------------
// phase 2: persistent recurrence. 64 blocks = 4 groups (16 batch rows) x 16
// slices (64 H-cols). Wh slice entirely in registers (32 x f16x8 per lane).
// LDS: state tile 32KB + 2.2KB transpose buffer.
__global__ __launch_bounds__(256, 1) void k_rnn(const f16* __restrict__ xph,
                                                const f16* __restrict__ WhT,
                                                f16* sbuf, unsigned* bar,
                                                float* __restrict__ out) {
  __shared__ __align__(16) unsigned char lds[32768 + 2176];
  unsigned char* stL  = lds;            // 16 rows x 2048 B (swizzled image)
  unsigned char* tbuf = lds + 32768;    // 16 x 136 B wave-local transpose
  const int tid = threadIdx.x;
  const int l = tid & 63, w = tid >> 6;          // w = n-tile 0..3
  const int lane15 = l & 15, sub = l >> 4;
  const int bid = blockIdx.x;
  const int group = (bid & 7) >> 1;              // 0..3 (XCD-pair colocated)
  const int slice = (bid >> 3) * 2 + (bid & 1);  // 0..15

  // entire Wh slice in registers: k = kk*32 + sub*8 .. +8, col = colL
  const int colL = slice * 64 + w * 16 + lane15; // this lane's output column
  f16x8 breg[32];
  {
    const f16* src = WhT + (size_t)colL * 1024 + sub * 8;
#pragma unroll
    for (int kk = 0; kk < 32; ++kk) breg[kk] = *(const f16x8*)(src + kk * 32);
  }
  const int rA = lane15, xA = rA & 7;
  const unsigned char* stLb = stL + rA * 2048;

  // staging / flag assignment: thread (p = tid>>4, q = tid&15) owns producer
  // p's 8B column chunk q. Producer p's slice occupies bytes [p*128, p*128+128)
  // of every image row (swizzle permutes only within those 8 slots).
  const int p = tid >> 4, q = tid & 15;
  unsigned* myflag   = bar + (group * 16 + slice) * 8;   // 32B spacing
  unsigned* pollflag = bar + (group * 16 + p) * 8;
  const bool do_poll = (p != slice);

  for (int t = 0; t < T_; ++t) {
    const char* ib = (const char*)sbuf + (size_t)(t & 1) * 131072 + group * 32768;
    char*       ob = (char*)sbuf + (size_t)((t + 1) & 1) * 131072 + group * 32768;

    // xp for this step (plain cached loads, issued before the poll)
    float xpv[4];
#pragma unroll
    for (int j = 0; j < 4; ++j)
      xpv[j] = (float)xph[(size_t)(t * 64 + group * 16 + sub * 4 + j) * 1024 + colL];

    // wait for this thread's producer (monotonic flag), then load its chunk
    if (t > 0 && do_poll) {
      while (__hip_atomic_load(pollflag, __ATOMIC_RELAXED,
                               __HIP_MEMORY_SCOPE_AGENT) < (unsigned)t) {}
    }
    {
      unsigned long long tmp[16];
      const char* src = ib + p * 128 + q * 8;
#pragma unroll
      for (int i = 0; i < 16; ++i)
        tmp[i] = __hip_atomic_load((const unsigned long long*)(src + i * 2048),
                                   __ATOMIC_RELAXED, __HIP_MEMORY_SCOPE_AGENT);
#pragma unroll
      for (int i = 0; i < 16; ++i)
        *(unsigned long long*)(stL + i * 2048 + p * 128 + q * 8) = tmp[i];
    }
    __syncthreads();

    f32x4 acc0 = {0.f,0.f,0.f,0.f}, acc1 = {0.f,0.f,0.f,0.f};
    f32x4 acc2 = {0.f,0.f,0.f,0.f}, acc3 = {0.f,0.f,0.f,0.f};
#pragma unroll
    for (int kk = 0; kk < 32; kk += 4) {
      f16x8 a0 = *(const f16x8*)(stLb + ((((kk + 0) * 4 + sub) ^ xA) << 4));
      f16x8 a1 = *(const f16x8*)(stLb + ((((kk + 1) * 4 + sub) ^ xA) << 4));
      f16x8 a2 = *(const f16x8*)(stLb + ((((kk + 2) * 4 + sub) ^ xA) << 4));
      f16x8 a3 = *(const f16x8*)(stLb + ((((kk + 3) * 4 + sub) ^ xA) << 4));
      acc0 = __builtin_amdgcn_mfma_f32_16x16x32_f16(a0, breg[kk + 0], acc0, 0, 0, 0);
      acc1 = __builtin_amdgcn_mfma_f32_16x16x32_f16(a1, breg[kk + 1], acc1, 0, 0, 0);
      acc2 = __builtin_amdgcn_mfma_f32_16x16x32_f16(a2, breg[kk + 2], acc2, 0, 0, 0);
      acc3 = __builtin_amdgcn_mfma_f32_16x16x32_f16(a3, breg[kk + 3], acc3, 0, 0, 0);
    }
    float rv[4];
#pragma unroll
    for (int j = 0; j < 4; ++j)
      rv[j] = acc0[j] + acc1[j] + acc2[j] + acc3[j] + xpv[j];

    if (t == T_ - 1) {
#pragma unroll
      for (int j = 0; j < 4; ++j)
        out[(size_t)(group * 16 + sub * 4 + j) * 1024 + colL] = tanhf(rv[j]);
      break;
    }

    // transpose this wave's 16x16 fragment (4 rows x 1 col per lane ->
    // 1 row x 4 cols per lane) through the wave-local tbuf region
#pragma unroll
    for (int j = 0; j < 4; ++j) {
      f16 hv = (f16)tanhf(rv[j]);
      *(f16*)(tbuf + (sub * 4 + j) * 136 + (w * 16 + lane15) * 2) = hv;
    }
    asm volatile("s_waitcnt lgkmcnt(0)" ::: "memory");
    const int rr = lane15, cg = sub;
    unsigned long long packed =
        *(const unsigned long long*)(tbuf + rr * 136 + (w * 16 + cg * 4) * 2);
    const int c0 = slice * 64 + w * 16 + cg * 4;           // 4-aligned col group
    const int byteoff = rr * 2048 + (((c0 >> 3) ^ (rr & 7)) << 4) + (c0 & 7) * 2;
    __hip_atomic_store((unsigned long long*)(ob + byteoff), packed,
                       __ATOMIC_RELAXED, __HIP_MEMORY_SCOPE_AGENT);

    // release: every wave drains its own coherent stores, barrier, then one
    // thread publishes the monotonic flag for this slice
    asm volatile("s_waitcnt vmcnt(0)" ::: "memory");
    __syncthreads();
    if (tid == 0)
      __hip_atomic_store(myflag, (unsigned)(t + 1),
                         __ATOMIC_RELAXED, __HIP_MEMORY_SCOPE_AGENT);
  }
}

// ---------------------------------------------------------------------------
extern "C" void kernel_launch(void* const* d_in, const int* in_sizes, int n_in,
                              void* d_out, int out_size, void* d_ws, size_t ws_size,
                              hipStream_t stream) {
  const float* x    = (const float*)d_in[0];
  const float* W    = (const float*)d_in[1];
  const float* bias = (const float*)d_in[2];
  float* out = (float*)d_out;
  char* w = (char*)d_ws;

  f16* xph = (f16*)(w + XPH_OFF);
  f16* WxT = (f16*)(w + WXT_OFF);
  f16* WhT = (f16*)(w + WHT_OFF);
  f16* sbuf = (f16*)(w + SBUF_OFF);
  unsigned* bar = (unsigned*)(w + BAR_OFF);

  // zero state image (state0 = 0) + flags, every launch
  hipMemsetAsync(w + SBUF_OFF, 0, 262144 + 2048, stream);

  k_prep<<<dim3(48 * 32), dim3(256), 0, stream>>>(W, WxT, WhT);
  k_xproj<<<dim3(512), dim3(256), 0, stream>>>(x, WxT, bias, xph);
  k_rnn<<<dim3(64), dim3(256), 0, stream>>>(xph, WhT, sbuf, bar, out);
}